// Round 1
// baseline (902.837 us; speedup 1.0000x reference)
//
#include <hip/hip_runtime.h>

// ---------------------------------------------------------------------------
// GCNDecoder: 2x GCNConv(64->64, sym-norm, self-loops) + ReLU, readout MLP
// 64->64(relu)->384, outputs (r[N,384], h[N,64]) concatenated in d_out.
// Strategy: build CSR-by-target once per launch (histogram -> scan -> fill),
// gather-based aggregation (wave per node, lane per feature), fp32 matmuls
// with W staged in LDS and wave-uniform row bases (s_load path).
// ---------------------------------------------------------------------------

__global__ void init_deg_cnt(float* deg, int* cnt, int n) {
    int i = blockIdx.x * 256 + threadIdx.x;
    if (i < n) { deg[i] = 1.0f; cnt[i] = 0; }   // deg starts at 1.0 (self-loop weight)
}

__global__ void hist_kernel(const int* __restrict__ col, const float* __restrict__ ew,
                            int* cnt, float* deg, int E) {
    int e = blockIdx.x * 256 + threadIdx.x;
    if (e < E) {
        int t = col[e];
        atomicAdd(&cnt[t], 1);
        atomicAdd(&deg[t], ew[e]);
    }
}

__global__ void dinv_kernel(float* deg, int n) {
    int i = blockIdx.x * 256 + threadIdx.x;
    if (i < n) { float d = deg[i]; deg[i] = d > 0.0f ? rsqrtf(d) : 0.0f; }
}

// Block scan: each block scans 1024 counts (4/thread), writes per-chunk
// exclusive prefix into excl[] and chunk total into bsum[blockIdx].
// Requires n % 4 == 0 (N=100000 ok).
__global__ void scan1(const int* __restrict__ cnt, int* __restrict__ excl,
                      int* __restrict__ bsum, int n) {
    __shared__ int lds[256];
    int t = threadIdx.x;
    int idx = blockIdx.x * 1024 + t * 4;
    int4 c = make_int4(0, 0, 0, 0);
    if (idx < n) c = *(const int4*)(cnt + idx);
    int s = c.x + c.y + c.z + c.w;
    lds[t] = s;
    __syncthreads();
    for (int off = 1; off < 256; off <<= 1) {
        int u = (t >= off) ? lds[t - off] : 0;
        __syncthreads();
        lds[t] += u;
        __syncthreads();
    }
    int incl = lds[t];
    if (t == 255) bsum[blockIdx.x] = incl;
    int e0 = incl - s;
    if (idx < n) {
        excl[idx + 0] = e0;
        excl[idx + 1] = e0 + c.x;
        excl[idx + 2] = e0 + c.x + c.y;
        excl[idx + 3] = e0 + c.x + c.y + c.z;
    }
}

// Scan the (<=256) chunk totals to exclusive offsets, in place.
__global__ void scan2(int* bsum, int nb) {
    __shared__ int lds[256];
    int t = threadIdx.x;
    int v = (t < nb) ? bsum[t] : 0;
    lds[t] = v;
    __syncthreads();
    for (int off = 1; off < 256; off <<= 1) {
        int u = (t >= off) ? lds[t - off] : 0;
        __syncthreads();
        lds[t] += u;
        __syncthreads();
    }
    if (t < nb) bsum[t] = lds[t] - v;
}

// Add chunk offsets; produce final ptr[] and a fill-cursor copy pfill[].
__global__ void scan3(int* __restrict__ ptr, const int* __restrict__ bsum,
                      int* __restrict__ pfill, int n, int E) {
    int i = blockIdx.x * 256 + threadIdx.x;
    if (i < n) {
        int v = ptr[i] + bsum[i >> 10];
        ptr[i] = v;
        pfill[i] = v;
    }
    if (i == n) ptr[n] = E;
}

// Scatter each edge into its target's CSR slot; precompute norm coefficient.
__global__ void fill_kernel(const int* __restrict__ row, const int* __restrict__ col,
                            const float* __restrict__ ew, const float* __restrict__ dinv,
                            int* pfill, int* __restrict__ srcs, float* __restrict__ wsrt,
                            int E) {
    int e = blockIdx.x * 256 + threadIdx.x;
    if (e < E) {
        int t = col[e], s = row[e];
        int p = atomicAdd(&pfill[t], 1);
        srcs[p] = s;
        wsrt[p] = dinv[s] * ew[e] * dinv[t];
    }
}

// Gather aggregation + ReLU. One wave per node, lane = feature (64 feats).
__global__ void aggregate_kernel(const float* __restrict__ hin, float* __restrict__ hout,
                                 const int* __restrict__ ptr, const int* __restrict__ srcs,
                                 const float* __restrict__ wsrt, const float* __restrict__ dinv,
                                 int n) {
    int gid = blockIdx.x * blockDim.x + threadIdx.x;
    int node = __builtin_amdgcn_readfirstlane(gid >> 6);   // wave-uniform -> SGPR
    int lane = threadIdx.x & 63;
    if (node >= n) return;
    float di = dinv[node];
    float acc = hin[(size_t)node * 64 + lane] * (di * di);  // self-loop (ew=1)
    int b = ptr[node], e2 = ptr[node + 1];
    for (int e = b; e < e2; ++e) {
        int s = srcs[e];          // wave-uniform scalar load
        float w = wsrt[e];        // wave-uniform scalar load
        acc = fmaf(w, hin[(size_t)s * 64 + lane], acc);  // coalesced 256B gather
    }
    hout[(size_t)node * 64 + lane] = fmaxf(acc, 0.0f);
}

// out[r, coff+c] = sum_k A[r,k] * W[k, coff+c] (+bias) (+relu)
// Block: 256 threads = 4 waves x 16 rows. W 64x64 tile in LDS.
// Wave-uniform row base via readfirstlane -> A reads become s_load (SGPR),
// inner loop: 4 ds_read_b32 + 16 s_load_dwordx4 + 64 v_fma per k-chunk.
template <bool BIAS, bool RELU>
__global__ void transform_kernel(const float* __restrict__ A, const float* __restrict__ W,
                                 const float* __restrict__ bias, float* __restrict__ out,
                                 int n, int ldw, int ldo) {
    __shared__ float Wl[64 * 64];
    int t = threadIdx.x;
    int coff = blockIdx.y * 64;
    for (int i = t; i < 4096; i += 256) {
        int k = i >> 6, c = i & 63;
        Wl[i] = W[k * ldw + coff + c];
    }
    __syncthreads();
    int wv = t >> 6, lane = t & 63;
    int row0 = (blockIdx.x * 4 + wv) * 16;
    row0 = __builtin_amdgcn_readfirstlane(row0);
    if (row0 >= n) return;
    float bv = BIAS ? bias[coff + lane] : 0.0f;
    float acc[16];
#pragma unroll
    for (int i = 0; i < 16; i++) acc[i] = bv;
    const float* Ar = A + (size_t)row0 * 64;
    int nrows = n - row0;
    if (nrows > 16) nrows = 16;
    if (nrows == 16) {
        for (int k0 = 0; k0 < 64; k0 += 4) {
            float w0 = Wl[(k0 + 0) * 64 + lane];
            float w1 = Wl[(k0 + 1) * 64 + lane];
            float w2 = Wl[(k0 + 2) * 64 + lane];
            float w3 = Wl[(k0 + 3) * 64 + lane];
#pragma unroll
            for (int i = 0; i < 16; i++) {
                float4 a = *(const float4*)(Ar + i * 64 + k0);
                acc[i] = fmaf(a.x, w0, fmaf(a.y, w1, fmaf(a.z, w2, fmaf(a.w, w3, acc[i]))));
            }
        }
#pragma unroll
        for (int i = 0; i < 16; i++) {
            float v = acc[i];
            if (RELU) v = fmaxf(v, 0.0f);
            out[(size_t)(row0 + i) * ldo + coff + lane] = v;
        }
    } else {
        for (int k = 0; k < 64; k++) {
            float w = Wl[k * 64 + lane];
            for (int i = 0; i < nrows; i++) acc[i] = fmaf(Ar[i * 64 + k], w, acc[i]);
        }
        for (int i = 0; i < nrows; i++) {
            float v = acc[i];
            if (RELU) v = fmaxf(v, 0.0f);
            out[(size_t)(row0 + i) * ldo + coff + lane] = v;
        }
    }
}

extern "C" void kernel_launch(void* const* d_in, const int* in_sizes, int n_in,
                              void* d_out, int out_size, void* d_ws, size_t ws_size,
                              hipStream_t stream) {
    const float* x  = (const float*)d_in[0];
    const int*   ei = (const int*)d_in[1];
    const float* ew = (const float*)d_in[2];
    const float* W1 = (const float*)d_in[3];
    const float* W2 = (const float*)d_in[4];
    const float* A1 = (const float*)d_in[5];
    const float* b1 = (const float*)d_in[6];
    const float* A2 = (const float*)d_in[7];
    const float* b2 = (const float*)d_in[8];
    float* out = (float*)d_out;

    const int N = in_sizes[0] / 64;
    const int E = in_sizes[2];
    const int* row = ei;
    const int* col = ei + E;

    // Workspace layout (~65.3 MB total)
    char* p = (char*)d_ws;
    auto alloc = [&](size_t bytes) { void* r = (void*)p; p += (bytes + 255) & ~(size_t)255; return r; };
    float* deg  = (float*)alloc((size_t)N * 4);        // becomes dinv in place
    int*   cnt  = (int*)alloc((size_t)N * 4);          // becomes pfill in place
    int*   ptr  = (int*)alloc((size_t)(N + 1) * 4);
    int*   bsum = (int*)alloc(1024);
    int*   srcs = (int*)alloc((size_t)E * 4);
    float* wsrt = (float*)alloc((size_t)E * 4);
    float* h1   = (float*)alloc((size_t)N * 64 * 4);   // transform output / layer2 transform
    float* h2b  = (float*)alloc((size_t)N * 64 * 4);   // agg1 output / readout hidden
    float* dinv = deg;
    int* pfill = cnt;

    float* r_out = out;                       // [N, 384]
    float* h_out = out + (size_t)N * 384;     // [N, 64]

    int nb = (N + 1023) / 1024;               // 98 for N=100000 (<= 256)

    // --- CSR build (once per launch; shared by both GCN layers) ---
    init_deg_cnt<<<(N + 255) / 256, 256, 0, stream>>>(deg, cnt, N);
    hist_kernel<<<(E + 255) / 256, 256, 0, stream>>>(col, ew, cnt, deg, E);
    dinv_kernel<<<(N + 255) / 256, 256, 0, stream>>>(deg, N);
    scan1<<<nb, 256, 0, stream>>>(cnt, ptr, bsum, N);
    scan2<<<1, 256, 0, stream>>>(bsum, nb);
    scan3<<<(N + 256) / 256, 256, 0, stream>>>(ptr, bsum, pfill, N, E);
    fill_kernel<<<(E + 255) / 256, 256, 0, stream>>>(row, col, ew, dinv, pfill, srcs, wsrt, E);

    dim3 tgrid((N + 63) / 64, 1);
    dim3 aggrid(((size_t)N * 64 + 255) / 256);

    // --- GCN layer 1: h1 = x @ W1 ; agg1 = relu(aggregate(h1)) ---
    transform_kernel<false, false><<<tgrid, 256, 0, stream>>>(x, W1, nullptr, h1, N, 64, 64);
    aggregate_kernel<<<aggrid, 256, 0, stream>>>(h1, h2b, ptr, srcs, wsrt, dinv, N);

    // --- GCN layer 2: h2 = agg1 @ W2 ; h = relu(aggregate(h2)) -> output ---
    transform_kernel<false, false><<<tgrid, 256, 0, stream>>>(h2b, W2, nullptr, h1, N, 64, 64);
    aggregate_kernel<<<aggrid, 256, 0, stream>>>(h1, h_out, ptr, srcs, wsrt, dinv, N);

    // --- Readout: t = relu(h @ A1 + b1); r = t @ A2 + b2 ---
    transform_kernel<true, true><<<tgrid, 256, 0, stream>>>(h_out, A1, b1, h2b, N, 64, 64);
    dim3 rgrid((N + 63) / 64, 6);
    transform_kernel<true, false><<<rgrid, 256, 0, stream>>>(h2b, A2, b2, r_out, N, 384, 384);
}

// Round 2
// 717.375 us; speedup vs baseline: 1.2585x; 1.2585x over previous
//
#include <hip/hip_runtime.h>

// ---------------------------------------------------------------------------
// GCNDecoder: 2x GCNConv(64->64, sym-norm, self-loops) + ReLU, readout MLP
// 64->64(relu)->384. Outputs (r[N,384], h[N,64]) concatenated in d_out.
//
// R2: two grouping strategies selected by ws_size:
//  - BUCKET (ws >= ~104MB): single atomic pass scatters edges into fixed
//    CAP=64 per-node buckets (1 atomic/edge total). dinv via wave-per-node
//    shuffle reduce; norms precomputed slot-parallel.
//  - CSR fallback: hist with PACKED u64 atomic (count<<32 | deg fixed-point)
//    -> 1 atomic/edge in hist (was 2), then scan + atomic fill.
// Aggregation: wave per node, lane = feature; edges stored interleaved
// (src, norm) as int2 -> one scalar dwordx2 load per edge; unrolled x2.
// ---------------------------------------------------------------------------

typedef unsigned long long ull;

// ============================ shared kernels ================================

// Gather aggregation + ReLU. One wave per node, lane = feature (64 feats).
// BUCKET: base = node*64, count = meta[node].
// CSR:    base = meta[node], count = meta[node+1]-base.
template <bool BUCKET>
__global__ void aggregate_kernel(const float* __restrict__ hin, float* __restrict__ hout,
                                 const int* __restrict__ meta,
                                 const int2* __restrict__ ent,
                                 const float* __restrict__ dinv, int n) {
    int gid = blockIdx.x * blockDim.x + threadIdx.x;
    int node = __builtin_amdgcn_readfirstlane(gid >> 6);   // wave-uniform -> SGPR
    int lane = threadIdx.x & 63;
    if (node >= n) return;
    float di = dinv[node];
    float acc0 = hin[(size_t)node * 64 + lane] * (di * di);  // self-loop (ew=1)
    float acc1 = 0.0f;
    int b, c;
    if (BUCKET) { b = node << 6; c = meta[node]; if (c > 64) c = 64; }
    else        { b = meta[node]; c = meta[node + 1] - b; }
    int e = b, end = b + c;
    for (; e + 2 <= end; e += 2) {
        int2 p0 = ent[e];       // wave-uniform scalar 8B load
        int2 p1 = ent[e + 1];
        acc0 = fmaf(__int_as_float(p0.y), hin[(size_t)p0.x * 64 + lane], acc0);
        acc1 = fmaf(__int_as_float(p1.y), hin[(size_t)p1.x * 64 + lane], acc1);
    }
    if (e < end) {
        int2 p0 = ent[e];
        acc0 = fmaf(__int_as_float(p0.y), hin[(size_t)p0.x * 64 + lane], acc0);
    }
    hout[(size_t)node * 64 + lane] = fmaxf(acc0 + acc1, 0.0f);
}

// out[r, coff+c] = sum_k A[r,k] * W[k, coff+c] (+bias) (+relu)
// Block: 256 threads = 4 waves x 16 rows. W 64x64 tile in LDS.
template <bool BIAS, bool RELU>
__global__ void transform_kernel(const float* __restrict__ A, const float* __restrict__ W,
                                 const float* __restrict__ bias, float* __restrict__ out,
                                 int n, int ldw, int ldo) {
    __shared__ float Wl[64 * 64];
    int t = threadIdx.x;
    int coff = blockIdx.y * 64;
    for (int i = t; i < 4096; i += 256) {
        int k = i >> 6, c = i & 63;
        Wl[i] = W[k * ldw + coff + c];
    }
    __syncthreads();
    int wv = t >> 6, lane = t & 63;
    int row0 = (blockIdx.x * 4 + wv) * 16;
    row0 = __builtin_amdgcn_readfirstlane(row0);
    if (row0 >= n) return;
    float bv = BIAS ? bias[coff + lane] : 0.0f;
    float acc[16];
#pragma unroll
    for (int i = 0; i < 16; i++) acc[i] = bv;
    const float* Ar = A + (size_t)row0 * 64;
    int nrows = n - row0;
    if (nrows > 16) nrows = 16;
    if (nrows == 16) {
        for (int k0 = 0; k0 < 64; k0 += 4) {
            float w0 = Wl[(k0 + 0) * 64 + lane];
            float w1 = Wl[(k0 + 1) * 64 + lane];
            float w2 = Wl[(k0 + 2) * 64 + lane];
            float w3 = Wl[(k0 + 3) * 64 + lane];
#pragma unroll
            for (int i = 0; i < 16; i++) {
                float4 a = *(const float4*)(Ar + i * 64 + k0);
                acc[i] = fmaf(a.x, w0, fmaf(a.y, w1, fmaf(a.z, w2, fmaf(a.w, w3, acc[i]))));
            }
        }
#pragma unroll
        for (int i = 0; i < 16; i++) {
            float v = acc[i];
            if (RELU) v = fmaxf(v, 0.0f);
            out[(size_t)(row0 + i) * ldo + coff + lane] = v;
        }
    } else {
        for (int k = 0; k < 64; k++) {
            float w = Wl[k * 64 + lane];
            for (int i = 0; i < nrows; i++) acc[i] = fmaf(Ar[i * 64 + k], w, acc[i]);
        }
        for (int i = 0; i < nrows; i++) {
            float v = acc[i];
            if (RELU) v = fmaxf(v, 0.0f);
            out[(size_t)(row0 + i) * ldo + coff + lane] = v;
        }
    }
}

// ============================ bucket path ===================================

__global__ void init_cnt(int* cnt, int n) {
    int i = blockIdx.x * 256 + threadIdx.x;
    if (i < n) cnt[i] = 0;
}

// One atomic per edge: claim a slot in the target's bucket, store (src, ew).
__global__ void bfill_kernel(const int* __restrict__ row, const int* __restrict__ col,
                             const float* __restrict__ ew, int* cnt, int2* __restrict__ bucket,
                             int E) {
    int e = blockIdx.x * 256 + threadIdx.x;
    if (e < E) {
        int t = col[e];
        int p = atomicAdd(&cnt[t], 1);
        if (p < 64) bucket[((size_t)t << 6) + p] = make_int2(row[e], __float_as_int(ew[e]));
    }
}

// Wave per node: shuffle-reduce bucket weights -> dinv = rsqrt(1 + sum(ew)).
__global__ void bdinv_kernel(const int* __restrict__ cnt, const int2* __restrict__ bucket,
                             float* __restrict__ dinv, int n) {
    int gid = blockIdx.x * blockDim.x + threadIdx.x;
    int node = gid >> 6;
    int lane = threadIdx.x & 63;
    if (node >= n) return;
    int c = cnt[node]; if (c > 64) c = 64;
    float w = (lane < c) ? __int_as_float(bucket[((size_t)node << 6) + lane].y) : 0.0f;
    for (int m = 32; m; m >>= 1) w += __shfl_xor(w, m, 64);
    if (lane == 0) dinv[node] = rsqrtf(1.0f + w);
}

// Slot-parallel: overwrite stored ew with dinv[s]*ew*dinv[t].
__global__ void bnorm_kernel(const int* __restrict__ cnt, int2* bucket,
                             const float* __restrict__ dinv, int n) {
    int gid = blockIdx.x * blockDim.x + threadIdx.x;
    int node = gid >> 6;
    int slot = threadIdx.x & 63;
    if (node >= n) return;
    int c = cnt[node]; if (c > 64) c = 64;
    if (slot < c) {
        size_t idx = ((size_t)node << 6) + slot;
        int2 p = bucket[idx];
        float w = dinv[p.x] * __int_as_float(p.y) * dinv[node];
        bucket[idx].y = __float_as_int(w);
    }
}

// ============================ CSR fallback path =============================

__global__ void init_dc(ull* dc, int n) {
    int i = blockIdx.x * 256 + threadIdx.x;
    if (i < n) dc[i] = 0ull;
}

// Packed histogram: one u64 atomic per edge. hi32 = count, lo32 = deg*2^20.
__global__ void hist_packed(const int* __restrict__ col, const float* __restrict__ ew,
                            ull* dc, int E) {
    int e = blockIdx.x * 256 + threadIdx.x;
    if (e < E) {
        int t = col[e];
        ull v = (1ull << 32) | (unsigned)lrintf(ew[e] * 1048576.0f);
        atomicAdd(&dc[t], v);
    }
}

__global__ void unpack_kernel(const ull* __restrict__ dc, int* __restrict__ cnt,
                              float* __restrict__ dinv, int n) {
    int i = blockIdx.x * 256 + threadIdx.x;
    if (i < n) {
        ull v = dc[i];
        cnt[i] = (int)(v >> 32);
        dinv[i] = rsqrtf(1.0f + (float)(unsigned)v * (1.0f / 1048576.0f));
    }
}

// Block scan: each block scans 1024 counts (4/thread). Requires n % 4 == 0.
__global__ void scan1(const int* __restrict__ cnt, int* __restrict__ excl,
                      int* __restrict__ bsum, int n) {
    __shared__ int lds[256];
    int t = threadIdx.x;
    int idx = blockIdx.x * 1024 + t * 4;
    int4 c = make_int4(0, 0, 0, 0);
    if (idx < n) c = *(const int4*)(cnt + idx);
    int s = c.x + c.y + c.z + c.w;
    lds[t] = s;
    __syncthreads();
    for (int off = 1; off < 256; off <<= 1) {
        int u = (t >= off) ? lds[t - off] : 0;
        __syncthreads();
        lds[t] += u;
        __syncthreads();
    }
    int incl = lds[t];
    if (t == 255) bsum[blockIdx.x] = incl;
    int e0 = incl - s;
    if (idx < n) {
        excl[idx + 0] = e0;
        excl[idx + 1] = e0 + c.x;
        excl[idx + 2] = e0 + c.x + c.y;
        excl[idx + 3] = e0 + c.x + c.y + c.z;
    }
}

__global__ void scan2(int* bsum, int nb) {
    __shared__ int lds[256];
    int t = threadIdx.x;
    int v = (t < nb) ? bsum[t] : 0;
    lds[t] = v;
    __syncthreads();
    for (int off = 1; off < 256; off <<= 1) {
        int u = (t >= off) ? lds[t - off] : 0;
        __syncthreads();
        lds[t] += u;
        __syncthreads();
    }
    if (t < nb) bsum[t] = lds[t] - v;
}

__global__ void scan3(int* __restrict__ ptr, const int* __restrict__ bsum,
                      int* __restrict__ pfill, int n, int E) {
    int i = blockIdx.x * 256 + threadIdx.x;
    if (i < n) {
        int v = ptr[i] + bsum[i >> 10];
        ptr[i] = v;
        pfill[i] = v;
    }
    if (i == n) ptr[n] = E;
}

// Scatter each edge into its CSR slot, storing (src, norm) interleaved.
__global__ void fill_kernel(const int* __restrict__ row, const int* __restrict__ col,
                            const float* __restrict__ ew, const float* __restrict__ dinv,
                            int* pfill, int2* __restrict__ ent, int E) {
    int e = blockIdx.x * 256 + threadIdx.x;
    if (e < E) {
        int t = col[e], s = row[e];
        int p = atomicAdd(&pfill[t], 1);
        ent[p] = make_int2(s, __float_as_int(dinv[s] * ew[e] * dinv[t]));
    }
}

// ============================ launch ========================================

extern "C" void kernel_launch(void* const* d_in, const int* in_sizes, int n_in,
                              void* d_out, int out_size, void* d_ws, size_t ws_size,
                              hipStream_t stream) {
    const float* x  = (const float*)d_in[0];
    const int*   ei = (const int*)d_in[1];
    const float* ew = (const float*)d_in[2];
    const float* W1 = (const float*)d_in[3];
    const float* W2 = (const float*)d_in[4];
    const float* A1 = (const float*)d_in[5];
    const float* b1 = (const float*)d_in[6];
    const float* A2 = (const float*)d_in[7];
    const float* b2 = (const float*)d_in[8];
    float* out = (float*)d_out;

    const int N = in_sizes[0] / 64;
    const int E = in_sizes[2];
    const int* row = ei;
    const int* col = ei + E;

    float* r_out = out;                       // [N, 384]
    float* h_out = out + (size_t)N * 384;     // [N, 64]

    dim3 tgrid((N + 63) / 64, 1);
    dim3 rgrid((N + 63) / 64, 6);
    int aggblocks = (int)(((size_t)N * 64 + 255) / 256);
    int nblk = (N + 255) / 256;
    int eblk = (E + 255) / 256;

    char* p = (char*)d_ws;
    auto alloc = [&](size_t bytes) { void* r = (void*)p; p += (bytes + 255) & ~(size_t)255; return r; };

    // Bucket path needs: cnt + dinv + bucket(N*64*8) + h1 + h2b
    size_t need_bucket = 256 * 8 + (size_t)N * 4 * 2 + ((size_t)N << 6) * 8 + (size_t)N * 64 * 4 * 2
                       + 64 * 1024;  // slack for 256B rounding
    if (ws_size >= need_bucket) {
        // ---------------- bucket path: 1 atomic pass total ----------------
        int*   cnt    = (int*)alloc((size_t)N * 4);
        float* dinv   = (float*)alloc((size_t)N * 4);
        int2*  bucket = (int2*)alloc(((size_t)N << 6) * 8);
        float* h1     = (float*)alloc((size_t)N * 64 * 4);
        float* h2b    = (float*)alloc((size_t)N * 64 * 4);

        init_cnt<<<nblk, 256, 0, stream>>>(cnt, N);
        bfill_kernel<<<eblk, 256, 0, stream>>>(row, col, ew, cnt, bucket, E);
        bdinv_kernel<<<aggblocks, 256, 0, stream>>>(cnt, bucket, dinv, N);
        bnorm_kernel<<<aggblocks, 256, 0, stream>>>(cnt, bucket, dinv, N);

        transform_kernel<false, false><<<tgrid, 256, 0, stream>>>(x, W1, nullptr, h1, N, 64, 64);
        aggregate_kernel<true><<<aggblocks, 256, 0, stream>>>(h1, h2b, cnt, bucket, dinv, N);
        transform_kernel<false, false><<<tgrid, 256, 0, stream>>>(h2b, W2, nullptr, h1, N, 64, 64);
        aggregate_kernel<true><<<aggblocks, 256, 0, stream>>>(h1, h_out, cnt, bucket, dinv, N);
        transform_kernel<true, true><<<tgrid, 256, 0, stream>>>(h_out, A1, b1, h2b, N, 64, 64);
        transform_kernel<true, false><<<rgrid, 256, 0, stream>>>(h2b, A2, b2, r_out, N, 384, 384);
    } else {
        // ---------------- CSR fallback: packed hist + scan + fill ---------
        ull*   dc   = (ull*)alloc((size_t)N * 8);
        int*   cnt  = (int*)alloc((size_t)N * 4);        // becomes pfill in place
        float* dinv = (float*)alloc((size_t)N * 4);
        int*   ptr  = (int*)alloc((size_t)(N + 1) * 4);
        int*   bsum = (int*)alloc(1024);
        int2*  ent  = (int2*)alloc((size_t)E * 8);
        float* h1   = (float*)alloc((size_t)N * 64 * 4);
        float* h2b  = (float*)alloc((size_t)N * 64 * 4);
        int*   pfill = cnt;
        int nb = (N + 1023) / 1024;

        init_dc<<<nblk, 256, 0, stream>>>(dc, N);
        hist_packed<<<eblk, 256, 0, stream>>>(col, ew, dc, E);
        unpack_kernel<<<nblk, 256, 0, stream>>>(dc, cnt, dinv, N);
        scan1<<<nb, 256, 0, stream>>>(cnt, ptr, bsum, N);
        scan2<<<1, 256, 0, stream>>>(bsum, nb);
        scan3<<<(N + 256) / 256, 256, 0, stream>>>(ptr, bsum, pfill, N, E);
        fill_kernel<<<eblk, 256, 0, stream>>>(row, col, ew, dinv, pfill, ent, E);

        transform_kernel<false, false><<<tgrid, 256, 0, stream>>>(x, W1, nullptr, h1, N, 64, 64);
        aggregate_kernel<false><<<aggblocks, 256, 0, stream>>>(h1, h2b, ptr, ent, dinv, N);
        transform_kernel<false, false><<<tgrid, 256, 0, stream>>>(h2b, W2, nullptr, h1, N, 64, 64);
        aggregate_kernel<false><<<aggblocks, 256, 0, stream>>>(h1, h_out, ptr, ent, dinv, N);
        transform_kernel<true, true><<<tgrid, 256, 0, stream>>>(h_out, A1, b1, h2b, N, 64, 64);
        transform_kernel<true, false><<<rgrid, 256, 0, stream>>>(h2b, A2, b2, r_out, N, 384, 384);
    }
}